// Round 1
// baseline (1162.987 us; speedup 1.0000x reference)
//
#include <hip/hip_runtime.h>
#include <hip/hip_bf16.h>
#include <math.h>

#define D_MODEL 1024
#define N_HEADS 16
#define N_KV 4
#define HEAD_DIM 64
#define SEQ 2048
#define BATCH 2
#define M_TOK (BATCH * SEQ)   // 4096 tokens

constexpr float CAP = 50.0f;
constexpr float EPS = 1e-5f;

// ---------------------------------------------------------------------------
// Tiled fp32 GEMM body: C[M x N] = A[M x K] @ B[K x N]
// 128x128 tile, BK=16, 256 threads, 8x8 per-thread microtile.
// A staged k-major (As[k][m]) via scalar transposed stores; B staged row-major
// with float4 stores. Inner reads are broadcast/conflict-free (strided by 16).
// ---------------------------------------------------------------------------
__device__ __forceinline__ void gemm_tile(const float* __restrict__ A,
                                          const float* __restrict__ Bm,
                                          float* __restrict__ C,
                                          int N, int K, int m0, int n0) {
  __shared__ float As[16][128];
  __shared__ float Bs[16][128];
  const int tid = threadIdx.x;
  const int tx = tid & 15, ty = tid >> 4;

  float acc[8][8];
#pragma unroll
  for (int i = 0; i < 8; ++i)
#pragma unroll
    for (int j = 0; j < 8; ++j) acc[i][j] = 0.f;

  for (int k0 = 0; k0 < K; k0 += 16) {
#pragma unroll
    for (int i = 0; i < 2; ++i) {
      int t = tid + i * 256;              // 0..511 float4 slots (2048 floats)
      int m  = t >> 2;                    // 0..127
      int kk = (t & 3) * 4;               // 0,4,8,12
      const float4 a = *(const float4*)&A[(size_t)(m0 + m) * K + k0 + kk];
      As[kk + 0][m] = a.x; As[kk + 1][m] = a.y;
      As[kk + 2][m] = a.z; As[kk + 3][m] = a.w;
      int kb = t >> 5;                    // 0..15
      int n  = (t & 31) * 4;              // 0..124
      *(float4*)&Bs[kb][n] = *(const float4*)&Bm[(size_t)(k0 + kb) * N + n0 + n];
    }
    __syncthreads();
#pragma unroll
    for (int kk = 0; kk < 16; ++kk) {
      float a[8], b[8];
#pragma unroll
      for (int i = 0; i < 8; ++i) a[i] = As[kk][ty + i * 16];
#pragma unroll
      for (int j = 0; j < 8; ++j) b[j] = Bs[kk][tx + j * 16];
#pragma unroll
      for (int i = 0; i < 8; ++i)
#pragma unroll
        for (int j = 0; j < 8; ++j) acc[i][j] = fmaf(a[i], b[j], acc[i][j]);
    }
    __syncthreads();
  }
#pragma unroll
  for (int i = 0; i < 8; ++i) {
    size_t row = (size_t)(m0 + ty + i * 16);
#pragma unroll
    for (int j = 0; j < 8; ++j)
      C[row * N + n0 + tx + j * 16] = acc[i][j];
  }
}

// Fused QKV projection: grid.x = 12 tiles across concatenated N=1536.
__global__ __launch_bounds__(256) void qkv_kernel(const float* __restrict__ x,
                                                  const float* __restrict__ wq,
                                                  const float* __restrict__ wk,
                                                  const float* __restrict__ wv,
                                                  float* __restrict__ q,
                                                  float* __restrict__ k,
                                                  float* __restrict__ v) {
  const int nb = blockIdx.x;
  const int m0 = blockIdx.y * 128;
  const float* B; float* C; int N; int n0;
  if (nb < 8)       { B = wq; C = q; N = 1024; n0 = nb * 128; }
  else if (nb < 10) { B = wk; C = k; N = 256;  n0 = (nb - 8) * 128; }
  else              { B = wv; C = v; N = 256;  n0 = (nb - 10) * 128; }
  gemm_tile(x, B, C, N, D_MODEL, m0, n0);
}

__global__ __launch_bounds__(256) void oproj_kernel(const float* __restrict__ y,
                                                    const float* __restrict__ wo,
                                                    float* __restrict__ out) {
  gemm_tile(y, wo, out, D_MODEL, D_MODEL, blockIdx.y * 128, blockIdx.x * 128);
}

// ---------------------------------------------------------------------------
// RMSNorm (per head, 64 elems = 64 lanes) + RoPE, in place on q and k.
// One block per token; wave w does q-heads [4w..4w+3] and k-head w.
// ---------------------------------------------------------------------------
__global__ __launch_bounds__(256) void norm_rope_kernel(float* __restrict__ q,
                                                        float* __restrict__ k) {
  const int t = blockIdx.x;                 // token = b*SEQ + pos
  const int pos = t & (SEQ - 1);
  const int wv = threadIdx.x >> 6, lane = threadIdx.x & 63;
  const int i = lane & 31;

  // inv_freq = 1 / theta^(i/32), fp32 like the reference
  const float invf = 1.0f / powf(10000.0f, (float)i * (1.0f / 32.0f));
  const float ang = (float)pos * invf;
  float sn, cs;
  sincosf(ang, &sn, &cs);

#pragma unroll
  for (int hh = 0; hh < 4; ++hh) {
    const int h = wv * 4 + hh;
    const size_t idx = ((size_t)t * N_HEADS + h) * HEAD_DIM + lane;
    float val = q[idx];
    float ss = val * val;
#pragma unroll
    for (int off = 32; off; off >>= 1) ss += __shfl_xor(ss, off);
    val *= rsqrtf(ss * (1.0f / 64.0f) + EPS);
    const float partner = __shfl_xor(val, 32);
    q[idx] = (lane < 32) ? (val * cs - partner * sn) : (val * cs + partner * sn);
  }
  {
    const int h = wv;                       // 4 waves == 4 kv heads
    const size_t idx = ((size_t)t * N_KV + h) * HEAD_DIM + lane;
    float val = k[idx];
    float ss = val * val;
#pragma unroll
    for (int off = 32; off; off >>= 1) ss += __shfl_xor(ss, off);
    val *= rsqrtf(ss * (1.0f / 64.0f) + EPS);
    const float partner = __shfl_xor(val, 32);
    k[idx] = (lane < 32) ? (val * cs - partner * sn) : (val * cs + partner * sn);
  }
}

// ---------------------------------------------------------------------------
// Flash attention with tanh softcap. Block = (b,h) x 32 q-rows; 4 waves x 8
// rows; K/V tiles of 64 rows staged in LDS. lane = k-row for scores, lane = d
// for PV. Q and P kept transposed in LDS so 8 rows share each Ks/Vs read.
// ---------------------------------------------------------------------------
__global__ __launch_bounds__(256) void attn_kernel(const float* __restrict__ q,
                                                   const float* __restrict__ k,
                                                   const float* __restrict__ v,
                                                   float* __restrict__ y) {
  __shared__ float Ks[64][65];    // [k-row][d], stride 65 -> conflict-free
  __shared__ float Vs[64][65];
  __shared__ float Qt[64][36];    // [d][q-row], 36*4B = 144B rows (16B aligned)
  __shared__ float Pt[4][64][8];  // [wave][k-row][q-row]

  const int bh = blockIdx.x;
  const int b = bh >> 4, h = bh & 15;
  const int hkv = h >> 2;
  const int q0 = blockIdx.y * 32;
  const int wv = threadIdx.x >> 6, lane = threadIdx.x & 63;

  const float qscale = 0.125f / CAP;   // 1/sqrt(64)/cap folded into Q
#pragma unroll
  for (int r = 0; r < 8; ++r) {
    const int row = wv * 8 + r;
    Qt[lane][row] =
        q[(((size_t)b * SEQ + q0 + row) * N_HEADS + h) * HEAD_DIM + lane] * qscale;
  }

  float m_r[8], l_r[8], o_r[8];
#pragma unroll
  for (int r = 0; r < 8; ++r) { m_r[r] = -1e30f; l_r[r] = 0.f; o_r[r] = 0.f; }

  const int ktiles = (q0 + 32 + 63) >> 6;
  for (int kt = 0; kt < ktiles; ++kt) {
    const int k0 = kt << 6;
    __syncthreads();                       // all waves done with prior tile
#pragma unroll
    for (int i = 0; i < 4; ++i) {
      int t = threadIdx.x + i * 256;       // 1024 float4 slots
      int row = t >> 4, d = (t & 15) * 4;
      size_t g = (((size_t)b * SEQ + k0 + row) * N_KV + hkv) * HEAD_DIM + d;
      float4 k4 = *(const float4*)&k[g];
      Ks[row][d] = k4.x; Ks[row][d + 1] = k4.y; Ks[row][d + 2] = k4.z; Ks[row][d + 3] = k4.w;
      float4 v4 = *(const float4*)&v[g];
      Vs[row][d] = v4.x; Vs[row][d + 1] = v4.y; Vs[row][d + 2] = v4.z; Vs[row][d + 3] = v4.w;
    }
    __syncthreads();

    // ---- scores: lane = k-row, 8 q-rows share each Ks read ----
    float s[8];
#pragma unroll
    for (int r = 0; r < 8; ++r) s[r] = 0.f;
#pragma unroll 4
    for (int d = 0; d < 64; ++d) {
      const float ks = Ks[lane][d];
      const float4 qa = *(const float4*)&Qt[d][wv * 8];
      const float4 qb = *(const float4*)&Qt[d][wv * 8 + 4];
      s[0] = fmaf(qa.x, ks, s[0]); s[1] = fmaf(qa.y, ks, s[1]);
      s[2] = fmaf(qa.z, ks, s[2]); s[3] = fmaf(qa.w, ks, s[3]);
      s[4] = fmaf(qb.x, ks, s[4]); s[5] = fmaf(qb.y, ks, s[5]);
      s[6] = fmaf(qb.z, ks, s[6]); s[7] = fmaf(qb.w, ks, s[7]);
    }

    // ---- softcap + causal mask + online softmax per row ----
    float corr[8];
    const int kg = k0 + lane;
#pragma unroll
    for (int r = 0; r < 8; ++r) {
      const int qg = q0 + wv * 8 + r;
      float sc = (kg <= qg) ? tanhf(s[r]) * CAP : -1e30f;
      float mx = sc;
#pragma unroll
      for (int off = 32; off; off >>= 1) mx = fmaxf(mx, __shfl_xor(mx, off));
      const float m_new = fmaxf(m_r[r], mx);
      corr[r] = expf(m_r[r] - m_new);
      const float p = expf(sc - m_new);
      float ps = p;
#pragma unroll
      for (int off = 32; off; off >>= 1) ps += __shfl_xor(ps, off);
      l_r[r] = l_r[r] * corr[r] + ps;
      m_r[r] = m_new;
      Pt[wv][lane][r] = p;                 // same-wave LDS handoff
    }
#pragma unroll
    for (int r = 0; r < 8; ++r) o_r[r] *= corr[r];

    // ---- PV: lane = d, 8 q-rows share each Vs read ----
#pragma unroll 4
    for (int l = 0; l < 64; ++l) {
      const float vs = Vs[l][lane];
      const float4 pa = *(const float4*)&Pt[wv][l][0];
      const float4 pb = *(const float4*)&Pt[wv][l][4];
      o_r[0] = fmaf(pa.x, vs, o_r[0]); o_r[1] = fmaf(pa.y, vs, o_r[1]);
      o_r[2] = fmaf(pa.z, vs, o_r[2]); o_r[3] = fmaf(pa.w, vs, o_r[3]);
      o_r[4] = fmaf(pb.x, vs, o_r[4]); o_r[5] = fmaf(pb.y, vs, o_r[5]);
      o_r[6] = fmaf(pb.z, vs, o_r[6]); o_r[7] = fmaf(pb.w, vs, o_r[7]);
    }
  }

#pragma unroll
  for (int r = 0; r < 8; ++r) {
    const int row = q0 + wv * 8 + r;
    y[(((size_t)b * SEQ + row) * N_HEADS + h) * HEAD_DIM + lane] =
        o_r[r] / l_r[r];
  }
}

extern "C" void kernel_launch(void* const* d_in, const int* in_sizes, int n_in,
                              void* d_out, int out_size, void* d_ws, size_t ws_size,
                              hipStream_t stream) {
  (void)in_sizes; (void)n_in; (void)out_size; (void)ws_size;
  const float* x  = (const float*)d_in[0];
  const float* wq = (const float*)d_in[1];
  const float* wk = (const float*)d_in[2];
  const float* wv = (const float*)d_in[3];
  const float* wo = (const float*)d_in[4];
  float* out = (float*)d_out;

  // workspace layout (floats): q | k | v | y  == 40 MB total
  float* qb = (float*)d_ws;
  float* kb = qb + (size_t)M_TOK * (N_HEADS * HEAD_DIM);
  float* vb = kb + (size_t)M_TOK * (N_KV * HEAD_DIM);
  float* yb = vb + (size_t)M_TOK * (N_KV * HEAD_DIM);

  qkv_kernel<<<dim3(12, M_TOK / 128), 256, 0, stream>>>(x, wq, wk, wv, qb, kb, vb);
  norm_rope_kernel<<<dim3(M_TOK), 256, 0, stream>>>(qb, kb);
  attn_kernel<<<dim3(BATCH * N_HEADS, SEQ / 32), 256, 0, stream>>>(qb, kb, vb, yb);
  oproj_kernel<<<dim3(D_MODEL / 128, M_TOK / 128), 256, 0, stream>>>(yb, wo, out);
}

// Round 2
// 154.663 us; speedup vs baseline: 7.5195x; 7.5195x over previous
//
#include <hip/hip_runtime.h>
#include <hip/hip_bf16.h>
#include <math.h>

#define D_MODEL 1024
#define N_HEADS 16
#define N_KV 4
#define HEAD_DIM 64
#define SEQ 2048
#define BATCH 2
#define M_TOK (BATCH * SEQ)

typedef unsigned int u32;
typedef unsigned short u16;
typedef __attribute__((ext_vector_type(8))) short short8;
typedef __attribute__((ext_vector_type(4))) float f32x4;
typedef __attribute__((ext_vector_type(16))) float f32x16;

#define AS1 __attribute__((address_space(1)))
#define AS3 __attribute__((address_space(3)))

__device__ __forceinline__ u16 f2bf(float f) {
  union { __hip_bfloat16 h; u16 u; } c; c.h = __float2bfloat16(f); return c.u;
}
__device__ __forceinline__ u32 pk2(float a, float b) {
  return (u32)f2bf(a) | ((u32)f2bf(b) << 16);
}
__device__ __forceinline__ u32 cvtpk(float lo, float hi) {
  u32 r; asm("v_cvt_pk_bf16_f32 %0, %1, %2" : "=v"(r) : "v"(lo), "v"(hi)); return r;
}
__device__ __forceinline__ void plswap(u32& a, u32& b) {
  asm volatile("v_permlane32_swap_b32 %0, %1" : "+v"(a), "+v"(b));
}
__device__ __forceinline__ float exp2fast(float x) { return __builtin_amdgcn_exp2f(x); }
__device__ __forceinline__ float rcpfast(float x) { return __builtin_amdgcn_rcpf(x); }

// ---------------------------------------------------------------------------
// Transpose-cast: dst[n][k] = bf16(src[k][n]).  grid (N/32, K/32), 256 thr.
// dst row stride is always 1024 (= D_MODEL).
// ---------------------------------------------------------------------------
__global__ __launch_bounds__(256) void tcast_kernel(const float* __restrict__ src,
                                                    u16* __restrict__ dst, int N) {
  __shared__ float t[32][33];
  const int n0 = blockIdx.x << 5, k0 = blockIdx.y << 5;
  const int x = threadIdx.x & 31, y = threadIdx.x >> 5;  // y: 0..7
#pragma unroll
  for (int i = 0; i < 4; ++i) {
    int r = y + (i << 3);
    t[r][x] = src[(size_t)(k0 + r) * N + n0 + x];
  }
  __syncthreads();
#pragma unroll
  for (int i = 0; i < 4; ++i) {
    int r = y + (i << 3);
    dst[(size_t)(n0 + r) * 1024 + k0 + x] = f2bf(t[x][r]);
  }
}

// ---------------------------------------------------------------------------
// bf16 MFMA GEMM: C[M][N] f32 = A[M][K] @ B^T[N][K].  128x128 tile, BK=32,
// 256 thr (4 waves, each a 64x64 quadrant of 4x4 16x16x32 frags), double-buf.
// AF32: A is f32 (reg-staged + cast); else bf16 via global_load_lds.
// ---------------------------------------------------------------------------
template<bool AF32>
__global__ __launch_bounds__(256, 2) void gemm_kernel(const void* __restrict__ Ap,
                                                      const u16* __restrict__ BT,
                                                      float* __restrict__ C,
                                                      int K, int ldc) {
  __shared__ uint4 As[2][512];
  __shared__ uint4 Bs[2][512];
  const int tid = threadIdx.x;
  const int w = tid >> 6, l = tid & 63;
  const int wr = w >> 1, wc = w & 1;
  const int m0 = blockIdx.y << 7, n0 = blockIdx.x << 7;

  f32x4 acc[4][4];
#pragma unroll
  for (int m = 0; m < 4; ++m)
#pragma unroll
    for (int n = 0; n < 4; ++n)
#pragma unroll
      for (int j = 0; j < 4; ++j) acc[m][n][j] = 0.f;

  auto stageAB = [&](int buf, int k0) {
    if (AF32) {
      const float* Af = (const float*)Ap + (size_t)m0 * K + k0;
#pragma unroll
      for (int i = 0; i < 2; ++i) {
        int c = tid + (i << 8);           // 0..511 16B-chunks
        int row = c >> 2, q = c & 3;
        const float* g = Af + (size_t)row * K + (q << 3);
        float4 f0 = *(const float4*)g;
        float4 f1 = *(const float4*)(g + 4);
        uint4 u;
        u.x = pk2(f0.x, f0.y); u.y = pk2(f0.z, f0.w);
        u.z = pk2(f1.x, f1.y); u.w = pk2(f1.z, f1.w);
        *(uint4*)((char*)As[buf] + (row << 6) + (q << 4)) = u;
      }
    } else {
      const u16* Ab = (const u16*)Ap + (size_t)m0 * K + k0;
#pragma unroll
      for (int r = 0; r < 2; ++r) {
        int i = ((tid >> 6) << 1) + r;    // wave-uniform issue index
        int row = (i << 4) + ((tid & 63) >> 2);
        const u16* g = Ab + (size_t)row * K + ((tid & 3) << 3);
        __builtin_amdgcn_global_load_lds((const AS1 void*)g,
            (AS3 void*)((char*)As[buf] + (i << 10)), 16, 0, 0);
      }
    }
    const u16* Bb = BT + (size_t)n0 * K + k0;
#pragma unroll
    for (int r = 0; r < 2; ++r) {
      int i = ((tid >> 6) << 1) + r;
      int row = (i << 4) + ((tid & 63) >> 2);
      const u16* g = Bb + (size_t)row * K + ((tid & 3) << 3);
      __builtin_amdgcn_global_load_lds((const AS1 void*)g,
          (AS3 void*)((char*)Bs[buf] + (i << 10)), 16, 0, 0);
    }
  };

  const int KT = K >> 5;
  stageAB(0, 0);
#pragma unroll 1
  for (int kt = 0; kt < KT; ++kt) {
    __syncthreads();                        // drains vm/lgkm: buf[kt&1] ready
    if (kt + 1 < KT) stageAB((kt + 1) & 1, (kt + 1) << 5);
    const char* Ab = (const char*)As[kt & 1];
    const char* Bb = (const char*)Bs[kt & 1];
    short8 af[4], bf[4];
#pragma unroll
    for (int m = 0; m < 4; ++m)
      af[m] = *(const short8*)(Ab + ((wr * 64 + m * 16 + (l & 15)) << 6) + ((l >> 4) << 4));
#pragma unroll
    for (int n = 0; n < 4; ++n)
      bf[n] = *(const short8*)(Bb + ((wc * 64 + n * 16 + (l & 15)) << 6) + ((l >> 4) << 4));
#pragma unroll
    for (int m = 0; m < 4; ++m)
#pragma unroll
      for (int n = 0; n < 4; ++n)
        acc[m][n] = __builtin_amdgcn_mfma_f32_16x16x32_bf16(af[m], bf[n], acc[m][n], 0, 0, 0);
  }

#pragma unroll
  for (int m = 0; m < 4; ++m) {
    int row0 = m0 + wr * 64 + m * 16 + ((l >> 4) << 2);
#pragma unroll
    for (int n = 0; n < 4; ++n) {
      int col = n0 + wc * 64 + n * 16 + (l & 15);
#pragma unroll
      for (int j = 0; j < 4; ++j)
        C[(size_t)(row0 + j) * ldc + col] = acc[m][n][j];
    }
  }
}

// ---------------------------------------------------------------------------
// RMSNorm + RoPE on q,k (reads qkv f32 [tok][1536]); writes bf16 head-major
// Qbf [b][h][s][64] (with 1/(8*CAP) folded in) and Kbf [b][hkv][s][64].
// ---------------------------------------------------------------------------
__global__ __launch_bounds__(256) void normrope_kernel(const float* __restrict__ qkv,
                                                       u16* __restrict__ Qbf,
                                                       u16* __restrict__ Kbf) {
  const int t = blockIdx.x;
  const int pos = t & 2047, b = t >> 11;
  const int wv = threadIdx.x >> 6, lane = threadIdx.x & 63;
  const int fi = lane & 31;
  const float invf = 1.0f / powf(10000.0f, (float)fi * (1.0f / 32.0f));
  float sn, cs; sincosf((float)pos * invf, &sn, &cs);
  const float* row = qkv + (size_t)t * 1536;
#pragma unroll
  for (int hh = 0; hh < 4; ++hh) {
    const int h = wv * 4 + hh;
    float val = row[h * 64 + lane];
    float ss = val * val;
#pragma unroll
    for (int off = 32; off; off >>= 1) ss += __shfl_xor(ss, off);
    val *= rsqrtf(ss * (1.f / 64.f) + 1e-5f);
    float partner = __shfl_xor(val, 32);
    float o = (lane < 32) ? (val * cs - partner * sn) : (val * cs + partner * sn);
    Qbf[((size_t)(b * 16 + h) * 2048 + pos) * 64 + lane] = f2bf(o * 0.0025f);
  }
  {
    float val = row[1024 + wv * 64 + lane];
    float ss = val * val;
#pragma unroll
    for (int off = 32; off; off >>= 1) ss += __shfl_xor(ss, off);
    val *= rsqrtf(ss * (1.f / 64.f) + 1e-5f);
    float partner = __shfl_xor(val, 32);
    float o = (lane < 32) ? (val * cs - partner * sn) : (val * cs + partner * sn);
    Kbf[((size_t)(b * 4 + wv) * 2048 + pos) * 64 + lane] = f2bf(o);
  }
}

// ---------------------------------------------------------------------------
// V transpose-cast: Vt[b][hkv][d][s] bf16 from qkv f32 v-columns.
// grid (SEQ/64, B*N_KV), 256 thr, LDS 64x65 f32 tile.
// ---------------------------------------------------------------------------
__global__ __launch_bounds__(256) void vtrans_kernel(const float* __restrict__ qkv,
                                                     u16* __restrict__ Vt) {
  __shared__ float t[64][65];
  const int bkv = blockIdx.y;          // b*4 + hkv
  const int s0 = blockIdx.x << 6;
  const int r = threadIdx.x >> 4, c4 = (threadIdx.x & 15) << 2;
#pragma unroll
  for (int i = 0; i < 4; ++i) {
    int row = r + (i << 4);            // token row within tile
    const float* g = qkv + (size_t)(((bkv >> 2) * 2048 + s0 + row)) * 1536
                   + 1280 + ((bkv & 3) << 6) + c4;
    float4 v = *(const float4*)g;
    t[row][c4] = v.x; t[row][c4 + 1] = v.y; t[row][c4 + 2] = v.z; t[row][c4 + 3] = v.w;
  }
  __syncthreads();
#pragma unroll
  for (int i = 0; i < 4; ++i) {
    int d = r + (i << 4);
    uint2 u;
    u.x = pk2(t[c4][d], t[c4 + 1][d]);
    u.y = pk2(t[c4 + 2][d], t[c4 + 3][d]);
    *(uint2*)(Vt + (size_t)(bkv * 64 + d) * 2048 + s0 + c4) = u;
  }
}

// ---------------------------------------------------------------------------
// Flash attention, 32x32x16 bf16 MFMA, swapped-operand QK^T, in-register
// softmax + cvt_pk/permlane32_swap P handoff, V^T*P^T for PV.
// Block = (b,h) x 128 q-rows; 4 waves x 32 q-rows; KVBLK=64 double-buffered.
// ---------------------------------------------------------------------------
__device__ __forceinline__ void stage64(uint4* lds, const u16* g, int strideElems, int tid) {
#pragma unroll
  for (int i = 0; i < 2; ++i) {
    int c = tid + (i << 8);            // 512 16B-chunks: row=c>>3, off=c&7
    int row = c >> 3, off = c & 7;
    uint4 v = *(const uint4*)(g + (size_t)row * strideElems + (off << 3));
    int byte = ((row << 7) + (off << 4)) ^ ((row & 7) << 4);   // XOR swizzle
    *(uint4*)((char*)lds + byte) = v;
  }
}
__device__ __forceinline__ short8 rdfrag(const uint4* lds, int row, int cb) {
  int byte = ((row << 7) + cb) ^ ((row & 7) << 4);
  return *(const short8*)((const char*)lds + byte);
}

__global__ __launch_bounds__(256, 2) void attn_kernel(const u16* __restrict__ Qbf,
                                                      const u16* __restrict__ Kbf,
                                                      const u16* __restrict__ Vt,
                                                      u16* __restrict__ ybf) {
  __shared__ uint4 KV[4][512];         // K0 V0 K1 V1, each 64x64 bf16 swizzled
  const int tid = threadIdx.x;
  const int w = tid >> 6, l = tid & 63;
  const int ql = l & 31, myh = l >> 5;
  const int b = blockIdx.x >> 4, h = blockIdx.x & 15, hkv = h >> 2;
  const int qt = 15 - blockIdx.y;      // heavy blocks first
  const int q0 = qt << 7;
  const int qg = q0 + w * 32 + ql;     // this lane's q row (C column)

  const u16* Kg = Kbf + (((size_t)(b * 4 + hkv)) << 11) * 64;
  const u16* Vg = Vt + (((size_t)(b * 4 + hkv)) << 6) * 2048;

  short8 bq[4];
  {
    const u16* Qg = Qbf + ((size_t)((b * 16 + h) * 2048 + q0 + w * 32 + ql)) * 64 + myh * 8;
    bq[0] = *(const short8*)(Qg);
    bq[1] = *(const short8*)(Qg + 16);
    bq[2] = *(const short8*)(Qg + 32);
    bq[3] = *(const short8*)(Qg + 48);
  }

  f32x16 o0, o1;
#pragma unroll
  for (int i = 0; i < 16; ++i) { o0[i] = 0.f; o1[i] = 0.f; }
  float m_run = -1e30f, l_run = 0.f;

  const int KT = (q0 >> 6) + 2;
  stage64(KV[0], Kg, 64, tid);
  stage64(KV[1], Vg, 2048, tid);

  const float TL2E = 2.8853900817779268f;  // 2*log2(e)
  const float L2E = 1.4426950408889634f;

#pragma unroll 1
  for (int kt = 0; kt < KT; ++kt) {
    const int k0 = kt << 6;
    const int buf = kt & 1;
    __syncthreads();
    if (kt + 1 < KT) {
      stage64(KV[(buf ^ 1) << 1],       Kg + (size_t)(k0 + 64) * 64, 64, tid);
      stage64(KV[((buf ^ 1) << 1) + 1], Vg + (k0 + 64),              2048, tid);
    }
    const int qminw = q0 + w * 32;
    if (k0 > qminw + 31) continue;     // fully masked for this wave
    const bool full = (k0 + 63 <= qminw);
    const uint4* Kl = KV[buf << 1];
    const uint4* Vl = KV[(buf << 1) + 1];

    f32x16 s0, s1;                     // scores^T: col=q(l&31), row=k offset
#pragma unroll
    for (int i = 0; i < 16; ++i) { s0[i] = 0.f; s1[i] = 0.f; }
#pragma unroll
    for (int c = 0; c < 4; ++c) {
      short8 ak = rdfrag(Kl, ql, (c << 5) + (myh << 4));
      s0 = __builtin_amdgcn_mfma_f32_32x32x16_bf16(ak, bq[c], s0, 0, 0, 0);
    }
#pragma unroll
    for (int c = 0; c < 4; ++c) {
      short8 ak = rdfrag(Kl, 32 + ql, (c << 5) + (myh << 4));
      s1 = __builtin_amdgcn_mfma_f32_32x32x16_bf16(ak, bq[c], s1, 0, 0, 0);
    }

    // softcap: arg already (q.k)/(8*CAP); sc = 50*tanh = 50 - 100/(e^{2x}+1)
    float mloc = -1e30f;
    if (full) {
#pragma unroll
      for (int i = 0; i < 16; ++i) {
        float v = 50.f - 100.f * rcpfast(exp2fast(s0[i] * TL2E) + 1.f);
        s0[i] = v; mloc = fmaxf(mloc, v);
      }
#pragma unroll
      for (int i = 0; i < 16; ++i) {
        float v = 50.f - 100.f * rcpfast(exp2fast(s1[i] * TL2E) + 1.f);
        s1[i] = v; mloc = fmaxf(mloc, v);
      }
    } else {
#pragma unroll
      for (int i = 0; i < 16; ++i) {
        int kk = k0 + (i & 3) + ((i >> 2) << 3) + (myh << 2);
        float v = 50.f - 100.f * rcpfast(exp2fast(s0[i] * TL2E) + 1.f);
        v = (kk <= qg) ? v : -1e30f;
        s0[i] = v; mloc = fmaxf(mloc, v);
      }
#pragma unroll
      for (int i = 0; i < 16; ++i) {
        int kk = k0 + 32 + (i & 3) + ((i >> 2) << 3) + (myh << 2);
        float v = 50.f - 100.f * rcpfast(exp2fast(s1[i] * TL2E) + 1.f);
        v = (kk <= qg) ? v : -1e30f;
        s1[i] = v; mloc = fmaxf(mloc, v);
      }
    }

    float mt = fmaxf(mloc, __shfl_xor(mloc, 32));
    float mn = fmaxf(m_run, mt);
    float corr = exp2fast((m_run - mn) * L2E);
    float ps = 0.f;
#pragma unroll
    for (int i = 0; i < 16; ++i) {
      float p0 = exp2fast((s0[i] - mn) * L2E); s0[i] = p0; ps += p0;
      float p1 = exp2fast((s1[i] - mn) * L2E); s1[i] = p1; ps += p1;
    }
    ps += __shfl_xor(ps, 32);
    l_run = l_run * corr + ps;
    m_run = mn;
#pragma unroll
    for (int i = 0; i < 16; ++i) { o0[i] *= corr; o1[i] *= corr; }

    // P -> bf16 B-frags: pa[c][j] = P[q=l&31][k = c*16 + myh*8 + j]
    short8 pa[4];
#pragma unroll
    for (int c = 0; c < 4; ++c) {
      const f32x16& P = (c < 2) ? s0 : s1;
      const int rb = (c & 1) << 3;
      u32 A = cvtpk(P[rb + 0], P[rb + 1]);
      u32 Cw = cvtpk(P[rb + 2], P[rb + 3]);
      u32 B = cvtpk(P[rb + 4], P[rb + 5]);
      u32 D = cvtpk(P[rb + 6], P[rb + 7]);
      plswap(A, B); plswap(Cw, D);
      union { u32 u[4]; short8 s; } pw;
      pw.u[0] = A; pw.u[1] = Cw; pw.u[2] = B; pw.u[3] = D;
      pa[c] = pw.s;
    }

    // O^T += V^T * P^T  (A = V^T rows d, B = P^T cols q)
#pragma unroll
    for (int c = 0; c < 4; ++c) {
      short8 av = rdfrag(Vl, ql, (c << 5) + (myh << 4));
      o0 = __builtin_amdgcn_mfma_f32_32x32x16_bf16(av, pa[c], o0, 0, 0, 0);
    }
#pragma unroll
    for (int c = 0; c < 4; ++c) {
      short8 av = rdfrag(Vl, 32 + ql, (c << 5) + (myh << 4));
      o1 = __builtin_amdgcn_mfma_f32_32x32x16_bf16(av, pa[c], o1, 0, 0, 0);
    }
  }

  float rl = rcpfast(l_run);
  u16* yr = ybf + ((size_t)(b * 2048 + q0 + w * 32 + ql)) * 1024 + h * 64;
#pragma unroll
  for (int i = 0; i < 16; i += 2) {
    int dof = (i & 3) + ((i >> 2) << 3) + (myh << 2);
    *(u32*)(yr + dof) = cvtpk(o0[i] * rl, o0[i + 1] * rl);
    *(u32*)(yr + 32 + dof) = cvtpk(o1[i] * rl, o1[i + 1] * rl);
  }
}

// ---------------------------------------------------------------------------
extern "C" void kernel_launch(void* const* d_in, const int* in_sizes, int n_in,
                              void* d_out, int out_size, void* d_ws, size_t ws_size,
                              hipStream_t stream) {
  (void)in_sizes; (void)n_in; (void)out_size; (void)ws_size;
  const float* x  = (const float*)d_in[0];
  const float* wq = (const float*)d_in[1];
  const float* wk = (const float*)d_in[2];
  const float* wv = (const float*)d_in[3];
  const float* wo = (const float*)d_in[4];
  float* out = (float*)d_out;

  char* ws = (char*)d_ws;
  // [0,24MiB): qkv f32.  ybf (8MiB) and woT (2MiB @ +8MiB) alias it after it dies.
  float* qkv = (float*)ws;
  u16* ybf = (u16*)ws;
  u16* woT = (u16*)(ws + (8u << 20));
  u16* wT  = (u16*)(ws + (24u << 20));   // 3 MiB: wq^T | wk^T | wv^T rows
  u16* Qbf = (u16*)(ws + (27u << 20));   // 8 MiB
  u16* Kbf = (u16*)(ws + (35u << 20));   // 2 MiB
  u16* Vt  = (u16*)(ws + (37u << 20));   // 2 MiB  (total 39 MiB)

  // weight transpose-casts
  tcast_kernel<<<dim3(32, 32), 256, 0, stream>>>(wq, wT, 1024);
  tcast_kernel<<<dim3(8, 32), 256, 0, stream>>>(wk, wT + 1024 * 1024, 256);
  tcast_kernel<<<dim3(8, 32), 256, 0, stream>>>(wv, wT + 1280 * 1024, 256);

  // fused QKV projection: C[4096][1536] = x @ [wq|wk|wv]
  gemm_kernel<true><<<dim3(12, 32), 256, 0, stream>>>(x, wT, qkv, 1024, 1536);

  normrope_kernel<<<dim3(M_TOK), 256, 0, stream>>>(qkv, Qbf, Kbf);
  vtrans_kernel<<<dim3(32, 8), 256, 0, stream>>>(qkv, Vt);

  // wo^T (after qkv f32 is dead in [8,10)MiB)
  tcast_kernel<<<dim3(32, 32), 256, 0, stream>>>(wo, woT, 1024);

  attn_kernel<<<dim3(32, 16), 256, 0, stream>>>(Qbf, Kbf, Vt, ybf);

  // output projection: out[4096][1024] = ybf @ wo
  gemm_kernel<false><<<dim3(8, 32), 256, 0, stream>>>(ybf, woT, out, 1024, 1024);
}